// Round 5
// baseline (160.287 us; speedup 1.0000x reference)
//
#include <hip/hip_runtime.h>

#define B_  8
#define TE_ 256
#define TD_ 128
#define HE_ 512

typedef __attribute__((ext_vector_type(4))) short short4v;
typedef __attribute__((ext_vector_type(8))) short short8v;
typedef __attribute__((ext_vector_type(4))) float f32x4;

__device__ __forceinline__ unsigned short f2bf(float x) {
  union { float f; unsigned u; } v; v.f = x;
  unsigned r = v.u + 0x7fff + ((v.u >> 16) & 1);   // RNE
  return (unsigned short)(r >> 16);
}
__device__ __forceinline__ float bf2f(unsigned short b) {
  union { float f; unsigned u; } v; v.u = ((unsigned)b) << 16;
  return v.f;
}

// ---- conv_all: both operand conversions in one launch ----
// blocks [0,1536): enc/dec -> A-hat [M,1536] = [hi|hi|lo]
// blocks [1536,1664): Wa/Ua -> BT [N,1536] = [hi|lo|hi] (transposed)
__global__ __launch_bounds__(256) void conv_all(
    const float* __restrict__ enc, const float* __restrict__ dec,
    const float* __restrict__ Wa, const float* __restrict__ Ua,
    short* __restrict__ AE, short* __restrict__ AD,
    short* __restrict__ BTW, short* __restrict__ BTU) {
  __shared__ float sT[64][68];
  int bid = blockIdx.x;
  const int tid = threadIdx.x;
  if (bid < 1536) {
    int idx = bid * 256 + tid;
    const int NE4 = (2048 * 512) / 4;
    const float* src; short* dst;
    if (idx < NE4) { src = enc; dst = AE; }
    else           { idx -= NE4; src = dec; dst = AD; }
    const int m = idx >> 7;
    const int k = (idx & 127) << 2;
    float4 v = *(const float4*)(src + (size_t)m * 512 + k);
    float vf[4] = {v.x, v.y, v.z, v.w};
    short4v hi, lo;
    for (int j = 0; j < 4; ++j) {
      unsigned short h = f2bf(vf[j]);
      hi[j] = (short)h;
      lo[j] = (short)f2bf(vf[j] - bf2f(h));
    }
    short* base = dst + (size_t)m * 1536 + k;
    *(short4v*)(base)        = hi;
    *(short4v*)(base + 512)  = hi;
    *(short4v*)(base + 1024) = lo;
    return;
  }
  bid -= 1536;
  const float* src; short* dst;
  if (bid < 64) { src = Wa; dst = BTW; }
  else          { bid -= 64; src = Ua; dst = BTU; }
  const int kt = (bid >> 3) * 64, nt = (bid & 7) * 64;
  const int lr = tid >> 4;
  const int lc = (tid & 15) * 4;
  for (int i = 0; i < 4; ++i) {
    float4 v = *(const float4*)(src + (size_t)(kt + lr + i * 16) * 512 + nt + lc);
    sT[lr + i * 16][lc + 0] = v.x;
    sT[lr + i * 16][lc + 1] = v.y;
    sT[lr + i * 16][lc + 2] = v.z;
    sT[lr + i * 16][lc + 3] = v.w;
  }
  __syncthreads();
  const int n_l = tid >> 2;
  const int kq  = (tid & 3) * 16;
  short8v hi0, hi1, lo0, lo1;
  for (int j = 0; j < 8; ++j) {
    float x0 = sT[kq + j][n_l];
    float x1 = sT[kq + 8 + j][n_l];
    unsigned short h0 = f2bf(x0), h1 = f2bf(x1);
    hi0[j] = (short)h0; lo0[j] = (short)f2bf(x0 - bf2f(h0));
    hi1[j] = (short)h1; lo1[j] = (short)f2bf(x1 - bf2f(h1));
  }
  short* base = dst + (size_t)(nt + n_l) * 1536 + kt + kq;
  *(short8v*)(base)        = hi0;
  *(short8v*)(base + 8)    = hi1;
  *(short8v*)(base + 512)  = lo0;
  *(short8v*)(base + 520)  = lo1;
  *(short8v*)(base + 1024) = hi0;
  *(short8v*)(base + 1032) = hi1;
}

// ---- gemm_mfma: 128x128 tile, BK=64, 96 blocks, 4 waves, 4x4 frags/wave ----
__global__ __launch_bounds__(256) void gemm_mfma(
    const short* __restrict__ AE, const short* __restrict__ AD,
    const short* __restrict__ BTW, const short* __restrict__ BTU,
    float* __restrict__ Ws, float* __restrict__ Uh) {
  __shared__ short sA[128][64];
  __shared__ short sB[128][64];
  int bid = blockIdx.x;
  const short *Asrc, *Bsrc; float* C;
  if (bid < 64) { Asrc = AE; Bsrc = BTW; C = Ws; }
  else          { bid -= 64; Asrc = AD; Bsrc = BTU; C = Uh; }
  const int m0 = (bid >> 2) * 128, n0 = (bid & 3) * 128;
  const int tid = threadIdx.x;
  const int srow = tid >> 1, sk = (tid & 1) * 32;   // 64 B per thread per tile
  const int wave = tid >> 6, lane = tid & 63;
  const int wr = (wave >> 1) * 64, wc = (wave & 1) * 64;
  const int fm = lane & 15, fk = (lane >> 4) * 8;
  const int r0 = (lane >> 4) * 4, ccol = lane & 15;
  f32x4 acc[4][4] = {};
  const short* Ap = Asrc + (size_t)(m0 + srow) * 1536 + sk;
  const short* Bp = Bsrc + (size_t)(n0 + srow) * 1536 + sk;
  for (int k0 = 0; k0 < 1536; k0 += 64) {
    short8v a[4], b[4];
#pragma unroll
    for (int q = 0; q < 4; ++q) {
      a[q] = *(const short8v*)(Ap + k0 + q * 8);
      b[q] = *(const short8v*)(Bp + k0 + q * 8);
    }
    __syncthreads();
#pragma unroll
    for (int q = 0; q < 4; ++q) {
      *(short8v*)&sA[srow][sk + q * 8] = a[q];
      *(short8v*)&sB[srow][sk + q * 8] = b[q];
    }
    __syncthreads();
#pragma unroll
    for (int s = 0; s < 64; s += 32) {
      short8v af[4], bf[4];
#pragma unroll
      for (int i = 0; i < 4; ++i) af[i] = *(const short8v*)&sA[wr + i * 16 + fm][s + fk];
#pragma unroll
      for (int j = 0; j < 4; ++j) bf[j] = *(const short8v*)&sB[wc + j * 16 + fm][s + fk];
#pragma unroll
      for (int i = 0; i < 4; ++i)
#pragma unroll
        for (int j = 0; j < 4; ++j)
          acc[i][j] = __builtin_amdgcn_mfma_f32_16x16x32_bf16(af[i], bf[j], acc[i][j], 0, 0, 0);
    }
  }
#pragma unroll
  for (int i = 0; i < 4; ++i)
#pragma unroll
    for (int j = 0; j < 4; ++j) {
      const int row = m0 + wr + i * 16 + r0;
      const int col = n0 + wc + j * 16 + ccol;
#pragma unroll
      for (int r = 0; r < 4; ++r)
        C[(size_t)(row + r) * 512 + col] = acc[i][j][r];
    }
}

// ---- attn_fused: 2 d's per block, 512 threads, 512 blocks ----
// phase1 per element: fma + exp2 + add + rcp + fma  (2 trans, 3 full-rate)
#define C2 2.8853900817779268f   // 2*log2(e)
__global__ __launch_bounds__(512) void attn_fused(
    const float* __restrict__ Ws, const float* __restrict__ Uh,
    const float* __restrict__ Va, const float* __restrict__ enc,
    float* __restrict__ c_out, float* __restrict__ e_out) {
  __shared__ float sUh[2][HE_];
  __shared__ float sV[HE_];
  __shared__ float sE[2][TE_];
  __shared__ float sRed[8];
  __shared__ float sNorm[2];
  const int tid = threadIdx.x;
  const int b  = blockIdx.x >> 6;
  const int d0 = (blockIdx.x & 63) * 2;
  if (tid < 256)
    ((float4*)sUh)[tid] = ((const float4*)(Uh + (size_t)(b * TD_ + d0) * HE_))[tid];
  else if (tid < 384)
    ((float4*)sV)[tid - 256] = ((const float4*)Va)[tid - 256];
  __syncthreads();
  const int lane = tid & 63, wave = tid >> 6;
  const int dl = wave >> 2;           // which d this wave works on
  const int tb = (wave & 3) * 64;     // t-range base
  const int h0 = lane << 3;
  float uhc[8], vv2[8], sumv = 0.f;
#pragma unroll
  for (int j = 0; j < 8; ++j) {
    const float vj = sV[h0 + j];
    sumv += vj;
    vv2[j] = 2.0f * vj;
    uhc[j] = C2 * sUh[dl][h0 + j];
  }
  const float* pw = Ws + (size_t)b * TE_ * HE_ + (size_t)tb * HE_ + h0;
  float4 a0 = *(const float4*)(pw);
  float4 a1 = *(const float4*)(pw + 4);
  float4 b0 = *(const float4*)(pw + HE_);
  float4 b1 = *(const float4*)(pw + HE_ + 4);
#define TELT(S, W, J) { \
    float arg = fmaf(C2, (W), uhc[J]); \
    float E = __builtin_amdgcn_exp2f(arg); \
    float r = __builtin_amdgcn_rcpf(E + 1.0f); \
    S = fmaf(-vv2[J], r, S); }
  for (int ti = 0; ti < 64; ti += 2) {
    const float* pn = pw + 2 * HE_;
    float4 n0 = *(const float4*)(pn);
    float4 n1 = *(const float4*)(pn + 4);
    float4 n2 = *(const float4*)(pn + HE_);
    float4 n3 = *(const float4*)(pn + HE_ + 4);
    float s0 = sumv, s1 = sumv;
    TELT(s0, a0.x, 0) TELT(s1, b0.x, 0)
    TELT(s0, a0.y, 1) TELT(s1, b0.y, 1)
    TELT(s0, a0.z, 2) TELT(s1, b0.z, 2)
    TELT(s0, a0.w, 3) TELT(s1, b0.w, 3)
    TELT(s0, a1.x, 4) TELT(s1, b1.x, 4)
    TELT(s0, a1.y, 5) TELT(s1, b1.y, 5)
    TELT(s0, a1.z, 6) TELT(s1, b1.z, 6)
    TELT(s0, a1.w, 7) TELT(s1, b1.w, 7)
#pragma unroll
    for (int off = 32; off; off >>= 1) {
      s0 += __shfl_down(s0, off, 64);
      s1 += __shfl_down(s1, off, 64);
    }
    if (lane == 0) { sE[dl][tb + ti] = s0; sE[dl][tb + ti + 1] = s1; }
    a0 = n0; a1 = n1; b0 = n2; b1 = n3;
    pw = pn;
  }
  __syncthreads();
  // softmax (no max-subtraction: |logit| <= sum|V| ~ 21, exp safe in fp32)
  const int d = tid >> 8, t = tid & 255;
  const float ex = __expf(sE[d][t]);
  float sum = ex;
#pragma unroll
  for (int off = 32; off; off >>= 1) sum += __shfl_down(sum, off, 64);
  if (lane == 0) sRed[wave] = sum;
  __syncthreads();
  if (tid < 2)
    sNorm[tid] = 1.0f / (sRed[tid * 4] + sRed[tid * 4 + 1] + sRed[tid * 4 + 2] + sRed[tid * 4 + 3]);
  __syncthreads();
  const float wgt = ex * sNorm[d];
  sE[d][t] = wgt;
  e_out[(size_t)(b * TD_ + d0 + d) * TE_ + t] = wgt;
  __syncthreads();
  // phase 3: c[b,d0+{0,1},h] ; thread owns h = tid
  float a0c = 0.f, a1c = 0.f;
  const float* ep = enc + (size_t)b * TE_ * HE_ + tid;
#pragma unroll 4
  for (int tt = 0; tt < TE_; ++tt) {
    const float ev = ep[(size_t)tt * HE_];
    a0c = fmaf(sE[0][tt], ev, a0c);
    a1c = fmaf(sE[1][tt], ev, a1c);
  }
  float* cp = c_out + (size_t)(b * TD_ + d0) * HE_ + tid;
  cp[0]   = a0c;
  cp[HE_] = a1c;
}

extern "C" void kernel_launch(void* const* d_in, const int* in_sizes, int n_in,
                              void* d_out, int out_size, void* d_ws, size_t ws_size,
                              hipStream_t stream) {
  const float* enc = (const float*)d_in[0];   // [8,256,512]
  const float* dec = (const float*)d_in[1];   // [8,128,512]
  const float* Wa  = (const float*)d_in[2];   // [512,512]
  const float* Ua  = (const float*)d_in[3];   // [512,512]
  const float* Va  = (const float*)d_in[4];   // [512,1]
  float* c_out = (float*)d_out;
  float* e_out = c_out + (size_t)B_ * TD_ * HE_;
  char* ws = (char*)d_ws;
  float* Ws  = (float*)(ws);                   // 4 MB
  float* Uh  = (float*)(ws + (4u << 20));      // 2 MB
  short* AE  = (short*)(ws + (6u << 20));      // 6 MB
  short* AD  = (short*)(ws + (12u << 20));     // 3 MB
  short* BTW = (short*)(ws + (15u << 20));     // 1.5 MB
  short* BTU = (short*)(ws + (15u << 20) + (3u << 19)); // 1.5 MB
  conv_all<<<1664, 256, 0, stream>>>(enc, dec, Wa, Ua, AE, AD, BTW, BTU);
  gemm_mfma<<<96, 256, 0, stream>>>(AE, AD, BTW, BTU, Ws, Uh);
  attn_fused<<<512, 512, 0, stream>>>(Ws, Uh, Va, enc, c_out, e_out);
}

// Round 6
// 136.819 us; speedup vs baseline: 1.1715x; 1.1715x over previous
//
#include <hip/hip_runtime.h>

#define B_  8
#define TE_ 256
#define TD_ 128
#define HE_ 512

typedef __attribute__((ext_vector_type(4))) short short4v;
typedef __attribute__((ext_vector_type(8))) short short8v;
typedef __attribute__((ext_vector_type(4))) float f32x4;

__device__ __forceinline__ unsigned short f2bf(float x) {
  union { float f; unsigned u; } v; v.f = x;
  unsigned r = v.u + 0x7fff + ((v.u >> 16) & 1);   // RNE
  return (unsigned short)(r >> 16);
}
__device__ __forceinline__ float bf2f(unsigned short b) {
  union { float f; unsigned u; } v; v.u = ((unsigned)b) << 16;
  return v.f;
}

// ---- conv_all ----
// blocks [0,1536): A = [enc;dec] fp32 [3072,512] -> Ahi/Alo bf16 [3072,512]
// blocks [1536,1664): Wa/Ua [k,n] -> transposed BThi/BTlo [n,512]
__global__ __launch_bounds__(256) void conv_all(
    const float* __restrict__ enc, const float* __restrict__ dec,
    const float* __restrict__ Wa, const float* __restrict__ Ua,
    short* __restrict__ Ahi, short* __restrict__ Alo,
    short* __restrict__ BWhi, short* __restrict__ BWlo,
    short* __restrict__ BUhi, short* __restrict__ BUlo) {
  __shared__ float sT[64][68];
  int bid = blockIdx.x;
  const int tid = threadIdx.x;
  if (bid < 1536) {
    int idx = bid * 256 + tid;          // [0, 393216)
    const int m = idx >> 7;
    const int k = (idx & 127) << 2;
    const float* src = (m < 2048) ? (enc + (size_t)m * 512 + k)
                                  : (dec + (size_t)(m - 2048) * 512 + k);
    float4 v = *(const float4*)src;
    float vf[4] = {v.x, v.y, v.z, v.w};
    short4v hi, lo;
    for (int j = 0; j < 4; ++j) {
      unsigned short h = f2bf(vf[j]);
      hi[j] = (short)h;
      lo[j] = (short)f2bf(vf[j] - bf2f(h));
    }
    *(short4v*)(Ahi + (size_t)m * 512 + k) = hi;
    *(short4v*)(Alo + (size_t)m * 512 + k) = lo;
    return;
  }
  bid -= 1536;
  const float* src; short *dhi, *dlo;
  if (bid < 64) { src = Wa; dhi = BWhi; dlo = BWlo; }
  else          { bid -= 64; src = Ua; dhi = BUhi; dlo = BUlo; }
  const int kt = (bid >> 3) * 64, nt = (bid & 7) * 64;
  const int lr = tid >> 4;
  const int lc = (tid & 15) * 4;
  for (int i = 0; i < 4; ++i) {
    float4 v = *(const float4*)(src + (size_t)(kt + lr + i * 16) * 512 + nt + lc);
    sT[lr + i * 16][lc + 0] = v.x;
    sT[lr + i * 16][lc + 1] = v.y;
    sT[lr + i * 16][lc + 2] = v.z;
    sT[lr + i * 16][lc + 3] = v.w;
  }
  __syncthreads();
  const int n_l = tid >> 2;
  const int kq  = (tid & 3) * 16;
  short8v h0v, h1v, l0v, l1v;
  for (int j = 0; j < 8; ++j) {
    float x0 = sT[kq + j][n_l];
    float x1 = sT[kq + 8 + j][n_l];
    unsigned short h0 = f2bf(x0), h1 = f2bf(x1);
    h0v[j] = (short)h0; l0v[j] = (short)f2bf(x0 - bf2f(h0));
    h1v[j] = (short)h1; l1v[j] = (short)f2bf(x1 - bf2f(h1));
  }
  size_t base = (size_t)(nt + n_l) * 512 + kt + kq;
  *(short8v*)(dhi + base)     = h0v;
  *(short8v*)(dhi + base + 8) = h1v;
  *(short8v*)(dlo + base)     = l0v;
  *(short8v*)(dlo + base + 8) = l1v;
}

// ---- gemm_mfma: C[3072,512] = A @ B, 3-term split-bf16 ----
// 128x64 tiles, BK=32 physical, 192 blocks (bid = nt*24 + mt -> XCD = mt%8),
// 4 waves each 64x32 quadrant; per k-step: 12 ds_read_b128 + 24 MFMA.
__global__ __launch_bounds__(256) void gemm_mfma(
    const short* __restrict__ Ahi, const short* __restrict__ Alo,
    const short* __restrict__ BWhi, const short* __restrict__ BWlo,
    const short* __restrict__ BUhi, const short* __restrict__ BUlo,
    float* __restrict__ C) {
  __shared__ short sAh[128][40];
  __shared__ short sAl[128][40];
  __shared__ short sBh[64][40];
  __shared__ short sBl[64][40];
  const int bid = blockIdx.x;
  const int mt = bid % 24, nt = bid / 24;
  const short *Bhp, *Blp;
  if (mt < 16) { Bhp = BWhi; Blp = BWlo; }
  else         { Bhp = BUhi; Blp = BUlo; }
  const int m0 = mt * 128;          // dec rows start at 2048 = 16*128
  const int n0 = nt * 64;
  const int tid = threadIdx.x;
  const int arow = tid >> 1, ak = (tid & 1) * 16;   // A: 128 rows x 2 halves
  const int brow = tid >> 2, bk = (tid & 3) * 8;    // B: 64 rows x 4 chunks
  const int wave = tid >> 6, lane = tid & 63;
  const int wr = (wave >> 1) * 64, wc = (wave & 1) * 32;
  const int fm = lane & 15, fk = (lane >> 4) * 8;
  const int r0 = (lane >> 4) * 4, ccol = lane & 15;
  f32x4 acc[4][2] = {};
  const short* Aph = Ahi + (size_t)(m0 + arow) * 512 + ak;
  const short* Apl = Alo + (size_t)(m0 + arow) * 512 + ak;
  const short* Bph = Bhp + (size_t)(n0 + brow) * 512 + bk;
  const short* Bpl = Blp + (size_t)(n0 + brow) * 512 + bk;
  short8v rah0 = *(const short8v*)(Aph);
  short8v rah1 = *(const short8v*)(Aph + 8);
  short8v ral0 = *(const short8v*)(Apl);
  short8v ral1 = *(const short8v*)(Apl + 8);
  short8v rbh  = *(const short8v*)(Bph);
  short8v rbl  = *(const short8v*)(Bpl);
  for (int it = 0; it < 16; ++it) {
    __syncthreads();
    *(short8v*)&sAh[arow][ak]     = rah0;
    *(short8v*)&sAh[arow][ak + 8] = rah1;
    *(short8v*)&sAl[arow][ak]     = ral0;
    *(short8v*)&sAl[arow][ak + 8] = ral1;
    *(short8v*)&sBh[brow][bk]     = rbh;
    *(short8v*)&sBl[brow][bk]     = rbl;
    __syncthreads();
    if (it < 15) {
      const int ko = (it + 1) * 32;
      rah0 = *(const short8v*)(Aph + ko);
      rah1 = *(const short8v*)(Aph + ko + 8);
      ral0 = *(const short8v*)(Apl + ko);
      ral1 = *(const short8v*)(Apl + ko + 8);
      rbh  = *(const short8v*)(Bph + ko);
      rbl  = *(const short8v*)(Bpl + ko);
    }
    short8v ah[4], al[4], bh2[2], bl2[2];
#pragma unroll
    for (int i = 0; i < 4; ++i) ah[i] = *(const short8v*)&sAh[wr + i * 16 + fm][fk];
#pragma unroll
    for (int j = 0; j < 2; ++j) {
      bh2[j] = *(const short8v*)&sBh[wc + j * 16 + fm][fk];
      bl2[j] = *(const short8v*)&sBl[wc + j * 16 + fm][fk];
    }
#pragma unroll
    for (int i = 0; i < 4; ++i)
#pragma unroll
      for (int j = 0; j < 2; ++j)
        acc[i][j] = __builtin_amdgcn_mfma_f32_16x16x32_bf16(ah[i], bh2[j], acc[i][j], 0, 0, 0);
#pragma unroll
    for (int i = 0; i < 4; ++i)
#pragma unroll
      for (int j = 0; j < 2; ++j)
        acc[i][j] = __builtin_amdgcn_mfma_f32_16x16x32_bf16(ah[i], bl2[j], acc[i][j], 0, 0, 0);
#pragma unroll
    for (int i = 0; i < 4; ++i) al[i] = *(const short8v*)&sAl[wr + i * 16 + fm][fk];
#pragma unroll
    for (int i = 0; i < 4; ++i)
#pragma unroll
      for (int j = 0; j < 2; ++j)
        acc[i][j] = __builtin_amdgcn_mfma_f32_16x16x32_bf16(al[i], bh2[j], acc[i][j], 0, 0, 0);
  }
#pragma unroll
  for (int i = 0; i < 4; ++i)
#pragma unroll
    for (int j = 0; j < 2; ++j) {
      const int row = m0 + wr + i * 16 + r0;
      const int col = n0 + wc + j * 16 + ccol;
#pragma unroll
      for (int r = 0; r < 4; ++r)
        C[(size_t)(row + r) * 512 + col] = acc[i][j][r];
    }
}

// ---- attn_fused: XCD-aware (b = bid&7), 2 d's per block, 512 thr ----
#define C2 2.8853900817779268f   // 2*log2(e)
__global__ __launch_bounds__(512) void attn_fused(
    const float* __restrict__ Ws, const float* __restrict__ Uh,
    const float* __restrict__ Va, const float* __restrict__ enc,
    float* __restrict__ c_out, float* __restrict__ e_out) {
  __shared__ float sUh[2][HE_];
  __shared__ float sV[HE_];
  __shared__ float sE[2][TE_];
  __shared__ float sRed[8];
  __shared__ float sNorm[2];
  const int tid = threadIdx.x;
  const int b  = blockIdx.x & 7;          // XCD-aligned b partition
  const int d0 = (blockIdx.x >> 3) * 2;
  if (tid < 256)
    ((float4*)sUh)[tid] = ((const float4*)(Uh + (size_t)(b * TD_ + d0) * HE_))[tid];
  else if (tid < 384)
    ((float4*)sV)[tid - 256] = ((const float4*)Va)[tid - 256];
  __syncthreads();
  const int lane = tid & 63, wave = tid >> 6;
  const int dl = wave >> 2;
  const int tb = (wave & 3) * 64;
  const int h0 = lane << 3;
  float uhc[8], vv2[8], sumv = 0.f;
#pragma unroll
  for (int j = 0; j < 8; ++j) {
    const float vj = sV[h0 + j];
    sumv += vj;
    vv2[j] = 2.0f * vj;
    uhc[j] = C2 * sUh[dl][h0 + j];
  }
  const float* pw = Ws + (size_t)b * TE_ * HE_ + (size_t)tb * HE_ + h0;
  float4 a0 = *(const float4*)(pw);
  float4 a1 = *(const float4*)(pw + 4);
  float4 b0 = *(const float4*)(pw + HE_);
  float4 b1 = *(const float4*)(pw + HE_ + 4);
#define TELT(S, W, J) { \
    float arg = fmaf(C2, (W), uhc[J]); \
    float E = __builtin_amdgcn_exp2f(arg); \
    float r = __builtin_amdgcn_rcpf(E + 1.0f); \
    S = fmaf(-vv2[J], r, S); }
  for (int ti = 0; ti < 64; ti += 2) {
    const float* pn = pw + 2 * HE_;
    float4 n0 = *(const float4*)(pn);
    float4 n1 = *(const float4*)(pn + 4);
    float4 n2 = *(const float4*)(pn + HE_);
    float4 n3 = *(const float4*)(pn + HE_ + 4);
    float s0 = sumv, s1 = sumv;
    TELT(s0, a0.x, 0) TELT(s1, b0.x, 0)
    TELT(s0, a0.y, 1) TELT(s1, b0.y, 1)
    TELT(s0, a0.z, 2) TELT(s1, b0.z, 2)
    TELT(s0, a0.w, 3) TELT(s1, b0.w, 3)
    TELT(s0, a1.x, 4) TELT(s1, b1.x, 4)
    TELT(s0, a1.y, 5) TELT(s1, b1.y, 5)
    TELT(s0, a1.z, 6) TELT(s1, b1.z, 6)
    TELT(s0, a1.w, 7) TELT(s1, b1.w, 7)
#pragma unroll
    for (int off = 32; off; off >>= 1) {
      s0 += __shfl_down(s0, off, 64);
      s1 += __shfl_down(s1, off, 64);
    }
    if (lane == 0) { sE[dl][tb + ti] = s0; sE[dl][tb + ti + 1] = s1; }
    a0 = n0; a1 = n1; b0 = n2; b1 = n3;
    pw = pn;
  }
  __syncthreads();
  // softmax (no max-subtraction: |logit| <= sum|V| ~ 21, exp safe in fp32)
  const int d = tid >> 8, t = tid & 255;
  const float ex = __expf(sE[d][t]);
  float sum = ex;
#pragma unroll
  for (int off = 32; off; off >>= 1) sum += __shfl_down(sum, off, 64);
  if (lane == 0) sRed[wave] = sum;
  __syncthreads();
  if (tid < 2)
    sNorm[tid] = 1.0f / (sRed[tid * 4] + sRed[tid * 4 + 1] + sRed[tid * 4 + 2] + sRed[tid * 4 + 3]);
  __syncthreads();
  const float wgt = ex * sNorm[d];
  sE[d][t] = wgt;
  e_out[(size_t)(b * TD_ + d0 + d) * TE_ + t] = wgt;
  __syncthreads();
  float a0c = 0.f, a1c = 0.f;
  const float* ep = enc + (size_t)b * TE_ * HE_ + tid;
#pragma unroll 4
  for (int tt = 0; tt < TE_; ++tt) {
    const float ev = ep[(size_t)tt * HE_];
    a0c = fmaf(sE[0][tt], ev, a0c);
    a1c = fmaf(sE[1][tt], ev, a1c);
  }
  float* cp = c_out + (size_t)(b * TD_ + d0) * HE_ + tid;
  cp[0]   = a0c;
  cp[HE_] = a1c;
}

extern "C" void kernel_launch(void* const* d_in, const int* in_sizes, int n_in,
                              void* d_out, int out_size, void* d_ws, size_t ws_size,
                              hipStream_t stream) {
  const float* enc = (const float*)d_in[0];   // [8,256,512]
  const float* dec = (const float*)d_in[1];   // [8,128,512]
  const float* Wa  = (const float*)d_in[2];   // [512,512]
  const float* Ua  = (const float*)d_in[3];   // [512,512]
  const float* Va  = (const float*)d_in[4];   // [512,1]
  float* c_out = (float*)d_out;
  float* e_out = c_out + (size_t)B_ * TD_ * HE_;
  char* ws = (char*)d_ws;
  float* Cws  = (float*)(ws);                          // [3072,512] fp32 = 6 MB (Ws rows 0..2047, Uh rows 2048..3071)
  short* Ahi  = (short*)(ws + (6u << 20));             // 3 MB
  short* Alo  = (short*)(ws + (9u << 20));             // 3 MB
  short* BWhi = (short*)(ws + (12u << 20));            // 512 KB
  short* BWlo = (short*)(ws + (12u << 20) + (1u << 19));
  short* BUhi = (short*)(ws + (13u << 20));
  short* BUlo = (short*)(ws + (13u << 20) + (1u << 19));
  const float* Ws = Cws;
  const float* Uh = Cws + (size_t)2048 * 512;
  conv_all<<<1664, 256, 0, stream>>>(enc, dec, Wa, Ua, Ahi, Alo, BWhi, BWlo, BUhi, BUlo);
  gemm_mfma<<<192, 256, 0, stream>>>(Ahi, Alo, BWhi, BWlo, BUhi, BUlo, Cws);
  attn_fused<<<512, 512, 0, stream>>>(Ws, Uh, Va, enc, c_out, e_out);
}

// Round 7
// 127.771 us; speedup vs baseline: 1.2545x; 1.0708x over previous
//
#include <hip/hip_runtime.h>

#define B_  8
#define TE_ 256
#define TD_ 128
#define HE_ 512

typedef __attribute__((ext_vector_type(4))) short short4v;
typedef __attribute__((ext_vector_type(8))) short short8v;
typedef __attribute__((ext_vector_type(4))) float f32x4;

__device__ __forceinline__ unsigned short f2bf(float x) {
  union { float f; unsigned u; } v; v.f = x;
  unsigned r = v.u + 0x7fff + ((v.u >> 16) & 1);   // RNE
  return (unsigned short)(r >> 16);
}
__device__ __forceinline__ float bf2f(unsigned short b) {
  union { float f; unsigned u; } v; v.u = ((unsigned)b) << 16;
  return v.f;
}

// lgkm-only barrier: safe because no cross-wave VMEM communication in-loop
// (prefetch global_loads are consumed by the SAME wave's ds_write, which the
// compiler guards with its own vmcnt wait). Avoids the vmcnt(0) drain that
// __syncthreads forces, so prefetch loads stay in flight across the barrier.
#define GBAR() asm volatile("s_waitcnt lgkmcnt(0)\n\ts_barrier" ::: "memory")

// ---- conv_all ----
// blocks [0,1536): A = [enc;dec] fp32 [3072,512] -> Ahi/Alo bf16 [3072,512]
// blocks [1536,1664): Wa/Ua [k,n] -> transposed BThi/BTlo [n,512]
__global__ __launch_bounds__(256) void conv_all(
    const float* __restrict__ enc, const float* __restrict__ dec,
    const float* __restrict__ Wa, const float* __restrict__ Ua,
    short* __restrict__ Ahi, short* __restrict__ Alo,
    short* __restrict__ BWhi, short* __restrict__ BWlo,
    short* __restrict__ BUhi, short* __restrict__ BUlo) {
  __shared__ float sT[64][68];
  int bid = blockIdx.x;
  const int tid = threadIdx.x;
  if (bid < 1536) {
    int idx = bid * 256 + tid;          // [0, 393216)
    const int m = idx >> 7;
    const int k = (idx & 127) << 2;
    const float* src = (m < 2048) ? (enc + (size_t)m * 512 + k)
                                  : (dec + (size_t)(m - 2048) * 512 + k);
    float4 v = *(const float4*)src;
    float vf[4] = {v.x, v.y, v.z, v.w};
    short4v hi, lo;
    for (int j = 0; j < 4; ++j) {
      unsigned short h = f2bf(vf[j]);
      hi[j] = (short)h;
      lo[j] = (short)f2bf(vf[j] - bf2f(h));
    }
    *(short4v*)(Ahi + (size_t)m * 512 + k) = hi;
    *(short4v*)(Alo + (size_t)m * 512 + k) = lo;
    return;
  }
  bid -= 1536;
  const float* src; short *dhi, *dlo;
  if (bid < 64) { src = Wa; dhi = BWhi; dlo = BWlo; }
  else          { bid -= 64; src = Ua; dhi = BUhi; dlo = BUlo; }
  const int kt = (bid >> 3) * 64, nt = (bid & 7) * 64;
  const int lr = tid >> 4;
  const int lc = (tid & 15) * 4;
  for (int i = 0; i < 4; ++i) {
    float4 v = *(const float4*)(src + (size_t)(kt + lr + i * 16) * 512 + nt + lc);
    sT[lr + i * 16][lc + 0] = v.x;
    sT[lr + i * 16][lc + 1] = v.y;
    sT[lr + i * 16][lc + 2] = v.z;
    sT[lr + i * 16][lc + 3] = v.w;
  }
  __syncthreads();
  const int n_l = tid >> 2;
  const int kq  = (tid & 3) * 16;
  short8v h0v, h1v, l0v, l1v;
  for (int j = 0; j < 8; ++j) {
    float x0 = sT[kq + j][n_l];
    float x1 = sT[kq + 8 + j][n_l];
    unsigned short h0 = f2bf(x0), h1 = f2bf(x1);
    h0v[j] = (short)h0; l0v[j] = (short)f2bf(x0 - bf2f(h0));
    h1v[j] = (short)h1; l1v[j] = (short)f2bf(x1 - bf2f(h1));
  }
  size_t base = (size_t)(nt + n_l) * 512 + kt + kq;
  *(short8v*)(dhi + base)     = h0v;
  *(short8v*)(dhi + base + 8) = h1v;
  *(short8v*)(dlo + base)     = l0v;
  *(short8v*)(dlo + base + 8) = l1v;
}

// ---- gemm_mfma: C[3072,512] = A @ B, 3-term split-bf16, dbuf single-barrier ----
// 128x64 tiles, BK=32, 192 blocks (bid%24 = mt -> XCD = mt%8), 4 waves.
__global__ __launch_bounds__(256) void gemm_mfma(
    const short* __restrict__ Ahi, const short* __restrict__ Alo,
    const short* __restrict__ BWhi, const short* __restrict__ BWlo,
    const short* __restrict__ BUhi, const short* __restrict__ BUlo,
    float* __restrict__ C) {
  __shared__ short sAh[2][128][40];
  __shared__ short sAl[2][128][40];
  __shared__ short sBh[2][64][40];
  __shared__ short sBl[2][64][40];
  const int bid = blockIdx.x;
  const int mt = bid % 24, nt = bid / 24;
  const short *Bhp, *Blp;
  if (mt < 16) { Bhp = BWhi; Blp = BWlo; }
  else         { Bhp = BUhi; Blp = BUlo; }
  const int m0 = mt * 128;          // dec rows start at 2048 = 16*128
  const int n0 = nt * 64;
  const int tid = threadIdx.x;
  const int arow = tid >> 1, ak = (tid & 1) * 16;   // A: 128 rows x 2 halves
  const int brow = tid >> 2, bk = (tid & 3) * 8;    // B: 64 rows x 4 chunks
  const int wave = tid >> 6, lane = tid & 63;
  const int wr = (wave >> 1) * 64, wc = (wave & 1) * 32;
  const int fm = lane & 15, fk = (lane >> 4) * 8;
  const int r0 = (lane >> 4) * 4, ccol = lane & 15;
  f32x4 acc[4][2] = {};
  const short* Aph = Ahi + (size_t)(m0 + arow) * 512 + ak;
  const short* Apl = Alo + (size_t)(m0 + arow) * 512 + ak;
  const short* Bph = Bhp + (size_t)(n0 + brow) * 512 + bk;
  const short* Bpl = Blp + (size_t)(n0 + brow) * 512 + bk;
  short8v rah0, rah1, ral0, ral1, rbh, rbl;
#define LOAD6(KO) { \
    rah0 = *(const short8v*)(Aph + (KO)); \
    rah1 = *(const short8v*)(Aph + (KO) + 8); \
    ral0 = *(const short8v*)(Apl + (KO)); \
    ral1 = *(const short8v*)(Apl + (KO) + 8); \
    rbh  = *(const short8v*)(Bph + (KO)); \
    rbl  = *(const short8v*)(Bpl + (KO)); }
#define STORE6(P) { \
    *(short8v*)&sAh[P][arow][ak]     = rah0; \
    *(short8v*)&sAh[P][arow][ak + 8] = rah1; \
    *(short8v*)&sAl[P][arow][ak]     = ral0; \
    *(short8v*)&sAl[P][arow][ak + 8] = ral1; \
    *(short8v*)&sBh[P][brow][bk]     = rbh; \
    *(short8v*)&sBl[P][brow][bk]     = rbl; }
  LOAD6(0);
  STORE6(0);
  LOAD6(32);
  __syncthreads();
  int p = 0;
  for (int it = 0; it < 16; ++it) {
    short8v ah[4], al[4], bh2[2], bl2[2];
#pragma unroll
    for (int i = 0; i < 4; ++i) ah[i] = *(const short8v*)&sAh[p][wr + i * 16 + fm][fk];
#pragma unroll
    for (int j = 0; j < 2; ++j) {
      bh2[j] = *(const short8v*)&sBh[p][wc + j * 16 + fm][fk];
      bl2[j] = *(const short8v*)&sBl[p][wc + j * 16 + fm][fk];
    }
#pragma unroll
    for (int i = 0; i < 4; ++i)
#pragma unroll
      for (int j = 0; j < 2; ++j)
        acc[i][j] = __builtin_amdgcn_mfma_f32_16x16x32_bf16(ah[i], bh2[j], acc[i][j], 0, 0, 0);
#pragma unroll
    for (int i = 0; i < 4; ++i)
#pragma unroll
      for (int j = 0; j < 2; ++j)
        acc[i][j] = __builtin_amdgcn_mfma_f32_16x16x32_bf16(ah[i], bl2[j], acc[i][j], 0, 0, 0);
#pragma unroll
    for (int i = 0; i < 4; ++i) al[i] = *(const short8v*)&sAl[p][wr + i * 16 + fm][fk];
#pragma unroll
    for (int i = 0; i < 4; ++i)
#pragma unroll
      for (int j = 0; j < 2; ++j)
        acc[i][j] = __builtin_amdgcn_mfma_f32_16x16x32_bf16(al[i], bh2[j], acc[i][j], 0, 0, 0);
    if (it < 15) STORE6(1 - p);          // compiler waits vmcnt for these regs
    if (it < 14) LOAD6((it + 2) * 32);   // in flight across next iteration
    GBAR();
    p ^= 1;
  }
#pragma unroll
  for (int i = 0; i < 4; ++i)
#pragma unroll
    for (int j = 0; j < 2; ++j) {
      const int row = m0 + wr + i * 16 + r0;
      const int col = n0 + wc + j * 16 + ccol;
#pragma unroll
      for (int r = 0; r < 4; ++r)
        C[(size_t)(row + r) * 512 + col] = acc[i][j][r];
    }
}

// ---- attn_fused: XCD-aware (b = bid&7), wave computes BOTH d's per Ws read ----
#define C2 2.8853900817779268f   // 2*log2(e)
__global__ __launch_bounds__(512) void attn_fused(
    const float* __restrict__ Ws, const float* __restrict__ Uh,
    const float* __restrict__ Va, const float* __restrict__ enc,
    float* __restrict__ c_out, float* __restrict__ e_out) {
  __shared__ float sUh[2][HE_];
  __shared__ float sV[HE_];
  __shared__ float sE[2][TE_];
  __shared__ float sRed[8];
  __shared__ float sNorm[2];
  const int tid = threadIdx.x;
  const int b  = blockIdx.x & 7;          // XCD-aligned b partition
  const int d0 = (blockIdx.x >> 3) * 2;
  if (tid < 256)
    ((float4*)sUh)[tid] = ((const float4*)(Uh + (size_t)(b * TD_ + d0) * HE_))[tid];
  else if (tid < 384)
    ((float4*)sV)[tid - 256] = ((const float4*)Va)[tid - 256];
  __syncthreads();
  const int lane = tid & 63, wave = tid >> 6;
  const int tb = wave << 5;               // 32 t per wave, both d's
  const int h0 = lane << 3;
  float uhc0[8], uhc1[8], vv2[8], sumv = 0.f;
#pragma unroll
  for (int j = 0; j < 8; ++j) {
    const float vj = sV[h0 + j];
    sumv += vj;
    vv2[j] = 2.0f * vj;
    uhc0[j] = C2 * sUh[0][h0 + j];
    uhc1[j] = C2 * sUh[1][h0 + j];
  }
  const float* pw = Ws + (size_t)b * TE_ * HE_ + (size_t)tb * HE_ + h0;
  float4 a0 = *(const float4*)(pw);
  float4 a1 = *(const float4*)(pw + 4);
#define TELT2(W, J) { \
    float g0 = fmaf(C2, (W), uhc0[J]); \
    float g1 = fmaf(C2, (W), uhc1[J]); \
    float E0 = __builtin_amdgcn_exp2f(g0); \
    float E1 = __builtin_amdgcn_exp2f(g1); \
    float r0 = __builtin_amdgcn_rcpf(E0 + 1.0f); \
    float r1 = __builtin_amdgcn_rcpf(E1 + 1.0f); \
    s0 = fmaf(-vv2[J], r0, s0); \
    s1 = fmaf(-vv2[J], r1, s1); }
  for (int ti = 0; ti < 32; ++ti) {
    const float* pn = pw + HE_;
    float4 n0 = *(const float4*)(pn);       // prefetch next t (safe: row exists)
    float4 n1 = *(const float4*)(pn + 4);
    float s0 = sumv, s1 = sumv;
    TELT2(a0.x, 0)
    TELT2(a0.y, 1)
    TELT2(a0.z, 2)
    TELT2(a0.w, 3)
    TELT2(a1.x, 4)
    TELT2(a1.y, 5)
    TELT2(a1.z, 6)
    TELT2(a1.w, 7)
#pragma unroll
    for (int off = 32; off; off >>= 1) {
      s0 += __shfl_down(s0, off, 64);
      s1 += __shfl_down(s1, off, 64);
    }
    if (lane == 0) { sE[0][tb + ti] = s0; sE[1][tb + ti] = s1; }
    a0 = n0; a1 = n1;
    pw = pn;
  }
  __syncthreads();
  // softmax (no max-subtraction: |logit| <= sum|V| ~ 21, exp safe in fp32)
  const int d = tid >> 8, t = tid & 255;
  const float ex = __expf(sE[d][t]);
  float sum = ex;
#pragma unroll
  for (int off = 32; off; off >>= 1) sum += __shfl_down(sum, off, 64);
  if (lane == 0) sRed[wave] = sum;
  __syncthreads();
  if (tid < 2)
    sNorm[tid] = 1.0f / (sRed[tid * 4] + sRed[tid * 4 + 1] + sRed[tid * 4 + 2] + sRed[tid * 4 + 3]);
  __syncthreads();
  const float wgt = ex * sNorm[d];
  sE[d][t] = wgt;
  e_out[(size_t)(b * TD_ + d0 + d) * TE_ + t] = wgt;
  __syncthreads();
  float a0c = 0.f, a1c = 0.f;
  const float* ep = enc + (size_t)b * TE_ * HE_ + tid;
#pragma unroll 4
  for (int tt = 0; tt < TE_; ++tt) {
    const float ev = ep[(size_t)tt * HE_];
    a0c = fmaf(sE[0][tt], ev, a0c);
    a1c = fmaf(sE[1][tt], ev, a1c);
  }
  float* cp = c_out + (size_t)(b * TD_ + d0) * HE_ + tid;
  cp[0]   = a0c;
  cp[HE_] = a1c;
}

extern "C" void kernel_launch(void* const* d_in, const int* in_sizes, int n_in,
                              void* d_out, int out_size, void* d_ws, size_t ws_size,
                              hipStream_t stream) {
  const float* enc = (const float*)d_in[0];   // [8,256,512]
  const float* dec = (const float*)d_in[1];   // [8,128,512]
  const float* Wa  = (const float*)d_in[2];   // [512,512]
  const float* Ua  = (const float*)d_in[3];   // [512,512]
  const float* Va  = (const float*)d_in[4];   // [512,1]
  float* c_out = (float*)d_out;
  float* e_out = c_out + (size_t)B_ * TD_ * HE_;
  char* ws = (char*)d_ws;
  float* Cws  = (float*)(ws);                          // [3072,512] fp32 = 6 MB
  short* Ahi  = (short*)(ws + (6u << 20));             // 3 MB
  short* Alo  = (short*)(ws + (9u << 20));             // 3 MB
  short* BWhi = (short*)(ws + (12u << 20));            // 512 KB
  short* BWlo = (short*)(ws + (12u << 20) + (1u << 19));
  short* BUhi = (short*)(ws + (13u << 20));
  short* BUlo = (short*)(ws + (13u << 20) + (1u << 19));
  const float* Ws = Cws;
  const float* Uh = Cws + (size_t)2048 * 512;
  conv_all<<<1664, 256, 0, stream>>>(enc, dec, Wa, Ua, Ahi, Alo, BWhi, BWlo, BUhi, BUlo);
  gemm_mfma<<<192, 256, 0, stream>>>(Ahi, Alo, BWhi, BWlo, BUhi, BUlo, Cws);
  attn_fused<<<512, 512, 0, stream>>>(Ws, Uh, Va, enc, c_out, e_out);
}

// Round 8
// 123.914 us; speedup vs baseline: 1.2935x; 1.0311x over previous
//
#include <hip/hip_runtime.h>

#define B_  8
#define TE_ 256
#define TD_ 128
#define HE_ 512

typedef __attribute__((ext_vector_type(4))) short short4v;
typedef __attribute__((ext_vector_type(8))) short short8v;
typedef __attribute__((ext_vector_type(4))) float f32x4;

__device__ __forceinline__ unsigned short f2bf(float x) {
  union { float f; unsigned u; } v; v.f = x;
  unsigned r = v.u + 0x7fff + ((v.u >> 16) & 1);   // RNE
  return (unsigned short)(r >> 16);
}
__device__ __forceinline__ float bf2f(unsigned short b) {
  union { float f; unsigned u; } v; v.u = ((unsigned)b) << 16;
  return v.f;
}

// ---- conv_all ----
// blocks [0,1536): A = [enc;dec] fp32 [3072,512] -> Ahi/Alo bf16 [3072,512]
// blocks [1536,1664): Wa/Ua [k,n] -> transposed BThi/BTlo [n,512]
__global__ __launch_bounds__(256) void conv_all(
    const float* __restrict__ enc, const float* __restrict__ dec,
    const float* __restrict__ Wa, const float* __restrict__ Ua,
    short* __restrict__ Ahi, short* __restrict__ Alo,
    short* __restrict__ BWhi, short* __restrict__ BWlo,
    short* __restrict__ BUhi, short* __restrict__ BUlo) {
  __shared__ float sT[64][68];
  int bid = blockIdx.x;
  const int tid = threadIdx.x;
  if (bid < 1536) {
    int idx = bid * 256 + tid;          // [0, 393216)
    const int m = idx >> 7;
    const int k = (idx & 127) << 2;
    const float* src = (m < 2048) ? (enc + (size_t)m * 512 + k)
                                  : (dec + (size_t)(m - 2048) * 512 + k);
    float4 v = *(const float4*)src;
    float vf[4] = {v.x, v.y, v.z, v.w};
    short4v hi, lo;
    for (int j = 0; j < 4; ++j) {
      unsigned short h = f2bf(vf[j]);
      hi[j] = (short)h;
      lo[j] = (short)f2bf(vf[j] - bf2f(h));
    }
    *(short4v*)(Ahi + (size_t)m * 512 + k) = hi;
    *(short4v*)(Alo + (size_t)m * 512 + k) = lo;
    return;
  }
  bid -= 1536;
  const float* src; short *dhi, *dlo;
  if (bid < 64) { src = Wa; dhi = BWhi; dlo = BWlo; }
  else          { bid -= 64; src = Ua; dhi = BUhi; dlo = BUlo; }
  const int kt = (bid >> 3) * 64, nt = (bid & 7) * 64;
  const int lr = tid >> 4;
  const int lc = (tid & 15) * 4;
  for (int i = 0; i < 4; ++i) {
    float4 v = *(const float4*)(src + (size_t)(kt + lr + i * 16) * 512 + nt + lc);
    sT[lr + i * 16][lc + 0] = v.x;
    sT[lr + i * 16][lc + 1] = v.y;
    sT[lr + i * 16][lc + 2] = v.z;
    sT[lr + i * 16][lc + 3] = v.w;
  }
  __syncthreads();
  const int n_l = tid >> 2;
  const int kq  = (tid & 3) * 16;
  short8v h0v, h1v, l0v, l1v;
  for (int j = 0; j < 8; ++j) {
    float x0 = sT[kq + j][n_l];
    float x1 = sT[kq + 8 + j][n_l];
    unsigned short h0 = f2bf(x0), h1 = f2bf(x1);
    h0v[j] = (short)h0; l0v[j] = (short)f2bf(x0 - bf2f(h0));
    h1v[j] = (short)h1; l1v[j] = (short)f2bf(x1 - bf2f(h1));
  }
  size_t base = (size_t)(nt + n_l) * 512 + kt + kq;
  *(short8v*)(dhi + base)     = h0v;
  *(short8v*)(dhi + base + 8) = h1v;
  *(short8v*)(dlo + base)     = l0v;
  *(short8v*)(dlo + base + 8) = l1v;
}

// ---- gemm_mfma: C[3072,512] = A @ B (3-term split-bf16) ----
// 128x64 tiles, BK=64, 192 blocks (XCD-affine), global_load_lds staging,
// 2-buffer pipeline with s_waitcnt vmcnt(12) (never 0 except tail).
// LDS buf layout (shorts): Ah[128][64] @0, Al @8192, Bh[64][64] @16384, Bl @20480.
// Chunk swizzle: slot16(r,c') holds global chunk c = c' ^ (r&7).
#define S_PER_BUF 24576
__global__ __launch_bounds__(256) void gemm_mfma(
    const short* __restrict__ Ahi, const short* __restrict__ Alo,
    const short* __restrict__ BWhi, const short* __restrict__ BWlo,
    const short* __restrict__ BUhi, const short* __restrict__ BUlo,
    float* __restrict__ C) {
  __shared__ __align__(16) short S[2 * S_PER_BUF];
  const int bid = blockIdx.x;
  const int mt = bid % 24, nt = bid / 24;
  const short* Bhp = (mt < 16) ? BWhi : BUhi;
  const short* Blp = (mt < 16) ? BWlo : BUlo;
  const int m0 = mt * 128, n0 = nt * 64;
  const int tid = threadIdx.x, w = tid >> 6, lane = tid & 63;
  // per-lane source offset inside an 8-row x 128B k-slab (xor chunk swizzle)
  const int laneoff = ((lane >> 3) << 10) + ((((lane & 7) ^ ((lane >> 3) & 7))) << 4);
  const char* gsrc[12]; int loff[12];
#pragma unroll
  for (int q = 0; q < 12; ++q) {
    const int v = w * 12 + q;
    const char* base; int vj, toff;
    if (v < 16)      { base = (const char*)(Ahi + (size_t)m0 * 512); vj = v;      toff = 0; }
    else if (v < 32) { base = (const char*)(Alo + (size_t)m0 * 512); vj = v - 16; toff = 8192; }
    else if (v < 40) { base = (const char*)(Bhp + (size_t)n0 * 512); vj = v - 32; toff = 16384; }
    else             { base = (const char*)(Blp + (size_t)n0 * 512); vj = v - 40; toff = 20480; }
    gsrc[q] = base + (size_t)vj * 8192 + laneoff;
    loff[q] = toff + vj * 512;
  }
#define ISSUE(IT, P) { const int koff_ = (IT) * 128; \
    _Pragma("unroll") \
    for (int q = 0; q < 12; ++q) \
      __builtin_amdgcn_global_load_lds(gsrc[q] + koff_, &S[(P) * S_PER_BUF + loff[q]], 16, 0, 0); }
  const int wr = (w >> 1) * 64, wc = (w & 1) * 32;
  const int fm = lane & 15, fchunk = lane >> 4;
  const int r0 = fchunk * 4, ccol = fm;
  f32x4 acc[4][2] = {};
  ISSUE(0, 0);
  ISSUE(1, 1);
  asm volatile("s_waitcnt vmcnt(12)\n\ts_barrier" ::: "memory");
  for (int it = 0; it < 8; ++it) {
    const int p = it & 1;
    const short* Sb = &S[p * S_PER_BUF];
#pragma unroll
    for (int s = 0; s < 2; ++s) {
      short8v ah[4], al[4], bh[2], bl[2];
      const int cc = s * 4 + fchunk;
#pragma unroll
      for (int i = 0; i < 4; ++i) {
        const int m = wr + i * 16 + fm;
        const int a16 = m * 8 + (cc ^ (m & 7));
        ah[i] = *(const short8v*)&Sb[a16 * 8];
        al[i] = *(const short8v*)&Sb[8192 + a16 * 8];
      }
#pragma unroll
      for (int j = 0; j < 2; ++j) {
        const int n = wc + j * 16 + fm;
        const int b16 = n * 8 + (cc ^ (n & 7));
        bh[j] = *(const short8v*)&Sb[16384 + b16 * 8];
        bl[j] = *(const short8v*)&Sb[20480 + b16 * 8];
      }
#pragma unroll
      for (int i = 0; i < 4; ++i)
#pragma unroll
        for (int j = 0; j < 2; ++j)
          acc[i][j] = __builtin_amdgcn_mfma_f32_16x16x32_bf16(ah[i], bh[j], acc[i][j], 0, 0, 0);
#pragma unroll
      for (int i = 0; i < 4; ++i)
#pragma unroll
        for (int j = 0; j < 2; ++j)
          acc[i][j] = __builtin_amdgcn_mfma_f32_16x16x32_bf16(ah[i], bl[j], acc[i][j], 0, 0, 0);
#pragma unroll
      for (int i = 0; i < 4; ++i)
#pragma unroll
        for (int j = 0; j < 2; ++j)
          acc[i][j] = __builtin_amdgcn_mfma_f32_16x16x32_bf16(al[i], bh[j], acc[i][j], 0, 0, 0);
    }
    if (it < 6) {
      asm volatile("s_barrier" ::: "memory");              // all reads of buf p retired
      ISSUE(it + 2, p);                                    // refill buf p
      asm volatile("s_waitcnt vmcnt(12)\n\ts_barrier" ::: "memory");  // batch it+1 landed
    } else if (it == 6) {
      asm volatile("s_waitcnt vmcnt(0)\n\ts_barrier" ::: "memory");   // tail: batch 7 landed
    }
  }
#pragma unroll
  for (int i = 0; i < 4; ++i)
#pragma unroll
    for (int j = 0; j < 2; ++j) {
      const int row = m0 + wr + i * 16 + r0;
      const int col = n0 + wc + j * 16 + ccol;
#pragma unroll
      for (int r = 0; r < 4; ++r)
        C[(size_t)(row + r) * 512 + col] = acc[i][j][r];
    }
#undef ISSUE
}

// ---- attn_fused: XCD-aware (b = bid&7), wave computes BOTH d's per Ws read ----
#define C2 2.8853900817779268f   // 2*log2(e)
__global__ __launch_bounds__(512) void attn_fused(
    const float* __restrict__ Ws, const float* __restrict__ Uh,
    const float* __restrict__ Va, const float* __restrict__ enc,
    float* __restrict__ c_out, float* __restrict__ e_out) {
  __shared__ float sUh[2][HE_];
  __shared__ float sV[HE_];
  __shared__ float sE[2][TE_];
  __shared__ float sRed[8];
  __shared__ float sNorm[2];
  const int tid = threadIdx.x;
  const int b  = blockIdx.x & 7;          // XCD-aligned b partition
  const int d0 = (blockIdx.x >> 3) * 2;
  if (tid < 256)
    ((float4*)sUh)[tid] = ((const float4*)(Uh + (size_t)(b * TD_ + d0) * HE_))[tid];
  else if (tid < 384)
    ((float4*)sV)[tid - 256] = ((const float4*)Va)[tid - 256];
  __syncthreads();
  const int lane = tid & 63, wave = tid >> 6;
  const int tb = wave << 5;               // 32 t per wave, both d's
  const int h0 = lane << 3;
  float uhc0[8], uhc1[8], vv2[8], sumv = 0.f;
#pragma unroll
  for (int j = 0; j < 8; ++j) {
    const float vj = sV[h0 + j];
    sumv += vj;
    vv2[j] = 2.0f * vj;
    uhc0[j] = C2 * sUh[0][h0 + j];
    uhc1[j] = C2 * sUh[1][h0 + j];
  }
  const float* pw = Ws + (size_t)b * TE_ * HE_ + (size_t)tb * HE_ + h0;
  float4 a0 = *(const float4*)(pw);
  float4 a1 = *(const float4*)(pw + 4);
#define TELT2(W, J) { \
    float g0 = fmaf(C2, (W), uhc0[J]); \
    float g1 = fmaf(C2, (W), uhc1[J]); \
    float E0 = __builtin_amdgcn_exp2f(g0); \
    float E1 = __builtin_amdgcn_exp2f(g1); \
    float r0_ = __builtin_amdgcn_rcpf(E0 + 1.0f); \
    float r1_ = __builtin_amdgcn_rcpf(E1 + 1.0f); \
    s0 = fmaf(-vv2[J], r0_, s0); \
    s1 = fmaf(-vv2[J], r1_, s1); }
  for (int ti = 0; ti < 32; ++ti) {
    const float* pn = pw + HE_;
    float4 n0 = *(const float4*)(pn);
    float4 n1 = *(const float4*)(pn + 4);
    float s0 = sumv, s1 = sumv;
    TELT2(a0.x, 0)
    TELT2(a0.y, 1)
    TELT2(a0.z, 2)
    TELT2(a0.w, 3)
    TELT2(a1.x, 4)
    TELT2(a1.y, 5)
    TELT2(a1.z, 6)
    TELT2(a1.w, 7)
#pragma unroll
    for (int off = 32; off; off >>= 1) {
      s0 += __shfl_down(s0, off, 64);
      s1 += __shfl_down(s1, off, 64);
    }
    if (lane == 0) { sE[0][tb + ti] = s0; sE[1][tb + ti] = s1; }
    a0 = n0; a1 = n1;
    pw = pn;
  }
  __syncthreads();
  // softmax (no max-subtraction: |logit| <= sum|V| ~ 21, exp safe in fp32)
  const int d = tid >> 8, t = tid & 255;
  const float ex = __expf(sE[d][t]);
  float sum = ex;
#pragma unroll
  for (int off = 32; off; off >>= 1) sum += __shfl_down(sum, off, 64);
  if (lane == 0) sRed[wave] = sum;
  __syncthreads();
  if (tid < 2)
    sNorm[tid] = 1.0f / (sRed[tid * 4] + sRed[tid * 4 + 1] + sRed[tid * 4 + 2] + sRed[tid * 4 + 3]);
  __syncthreads();
  const float wgt = ex * sNorm[d];
  sE[d][t] = wgt;
  e_out[(size_t)(b * TD_ + d0 + d) * TE_ + t] = wgt;
  __syncthreads();
  float a0c = 0.f, a1c = 0.f;
  const float* ep = enc + (size_t)b * TE_ * HE_ + tid;
#pragma unroll 4
  for (int tt = 0; tt < TE_; ++tt) {
    const float ev = ep[(size_t)tt * HE_];
    a0c = fmaf(sE[0][tt], ev, a0c);
    a1c = fmaf(sE[1][tt], ev, a1c);
  }
  float* cp = c_out + (size_t)(b * TD_ + d0) * HE_ + tid;
  cp[0]   = a0c;
  cp[HE_] = a1c;
}

extern "C" void kernel_launch(void* const* d_in, const int* in_sizes, int n_in,
                              void* d_out, int out_size, void* d_ws, size_t ws_size,
                              hipStream_t stream) {
  const float* enc = (const float*)d_in[0];   // [8,256,512]
  const float* dec = (const float*)d_in[1];   // [8,128,512]
  const float* Wa  = (const float*)d_in[2];   // [512,512]
  const float* Ua  = (const float*)d_in[3];   // [512,512]
  const float* Va  = (const float*)d_in[4];   // [512,1]
  float* c_out = (float*)d_out;
  float* e_out = c_out + (size_t)B_ * TD_ * HE_;
  char* ws = (char*)d_ws;
  float* Cws  = (float*)(ws);                          // [3072,512] fp32 = 6 MB
  short* Ahi  = (short*)(ws + (6u << 20));             // 3 MB
  short* Alo  = (short*)(ws + (9u << 20));             // 3 MB
  short* BWhi = (short*)(ws + (12u << 20));            // 512 KB
  short* BWlo = (short*)(ws + (12u << 20) + (1u << 19));
  short* BUhi = (short*)(ws + (13u << 20));
  short* BUlo = (short*)(ws + (13u << 20) + (1u << 19));
  const float* Ws = Cws;
  const float* Uh = Cws + (size_t)2048 * 512;
  conv_all<<<1664, 256, 0, stream>>>(enc, dec, Wa, Ua, Ahi, Alo, BWhi, BWlo, BUhi, BUlo);
  gemm_mfma<<<192, 256, 0, stream>>>(Ahi, Alo, BWhi, BWlo, BUhi, BUlo, Cws);
  attn_fused<<<512, 512, 0, stream>>>(Ws, Uh, Va, enc, c_out, e_out);
}